// Round 8
// baseline (161.912 us; speedup 1.0000x reference)
//
#include <hip/hip_runtime.h>
#include <cmath>

#define NDEV   100000
#define NBATCH 8192
#define CONTF  62
#define EMB    16
#define FEAT   94      // 62 + 16 + 16
#define KNBR   64
#define NH     4
#define OUTD   16
#define HOUT   64      // NH*OUTD
#define FUS    204     // 94 + 94 + 16
#define ALPHA  0.2f

#define NDEVG2  782    // ceil(100000/128) row-groups
#define NCOMBG2 64     // 8192/128 row-groups
#define KP      48     // K-pairs incl. zero pad (96 bf16 = 48 uints)
#define WROWS   68     // 64 W cols + 4 e-logit (a-weighted) cols

typedef unsigned short ushortT;
typedef unsigned int   uintT;
typedef ushortT ushort8v __attribute__((ext_vector_type(8)));
typedef short   short8  __attribute__((ext_vector_type(8)));
typedef float   float4v __attribute__((ext_vector_type(4)));

// ---------------- workspace layout (float slots) ----------------
// h_bf  : NDEV*64 bf16 = 3,200,000 @ 0   (12.8 MB)
// e_d   : NDEV*4       =   400,000 @ 3,200,000
// e_c   : NBATCH*4     =    32,768 @ 3,600,000
// wpack : 2*68*48 uint =     6,528 @ 3,632,768   (bf16x2-packed W^T+waug)

template <typename T>
__device__ __forceinline__ const T* uniform_ptr(const T* p) {
  uint64_t v = (uint64_t)(uintptr_t)p;
  uint32_t lo = __builtin_amdgcn_readfirstlane((uint32_t)v);
  uint32_t hi = __builtin_amdgcn_readfirstlane((uint32_t)(v >> 32));
  return (const T*)(uintptr_t)(((uint64_t)hi << 32) | lo);
}

__device__ __forceinline__ float bf2f(ushortT u) {
  return __uint_as_float(((unsigned int)u) << 16);
}
__device__ __forceinline__ ushortT f2bf(float f) {
  unsigned int i = __float_as_uint(f);
  unsigned int r = i + 0x7FFFu + ((i >> 16) & 1u);  // round-to-nearest-even
  return (ushortT)(r >> 16);
}
__device__ __forceinline__ uintT pack2(float lo, float hi) {
  return ((uintT)f2bf(hi) << 16) | (uintT)f2bf(lo);
}

union FragU { uint4 u; short8 s; };

// ---------------- K0: pack W^T -> bf16x2 once (layout [n][p], n=h*16+o) -----
// Rows 64..67: waug[hd][f] = sum_o W[hd][f][o] * a_seg[hd][o]  (e-logit cols).
__global__ __launch_bounds__(256) void k_prep(
    const float* __restrict__ Wd, const float* __restrict__ Wc,
    const float* __restrict__ aW,
    uintT* __restrict__ wpack) {
  const int e = blockIdx.x * 256 + threadIdx.x;   // 0..6527
  if (e >= 2 * WROWS * KP) return;
  const bool dev = e < WROWS * KP;
  const int i = dev ? e : e - WROWS * KP;
  const int n = i / KP, p = i - n * KP;
  const float* __restrict__ Ws = dev ? Wd : Wc;
  uintT v = 0u;
  if (p < 47) {
    if (n < 64) {
      const int h = n >> 4, o = n & 15;
      const float lo = Ws[(h * FEAT + 2 * p) * OUTD + o];
      const float hi = Ws[(h * FEAT + 2 * p + 1) * OUTD + o];
      v = pack2(lo, hi);
    } else {
      const int hd = n - 64;                       // 0..3
      const float* __restrict__ av = aW + hd * 2 * OUTD + (dev ? OUTD : 0);
      float lo = 0.f, hi = 0.f;
#pragma unroll
      for (int o = 0; o < OUTD; ++o) {
        lo = fmaf(Ws[(hd * FEAT + 2 * p) * OUTD + o], av[o], lo);
        hi = fmaf(Ws[(hd * FEAT + 2 * p + 1) * OUTD + o], av[o], hi);
      }
      v = pack2(lo, hi);
    }
  }
  wpack[e] = v;
}

// ---------------- K1: X[row,94] @ W[94,68] via bf16 MFMA, 128 rows/block ----
// 4 waves; wave wv owns row-tiles {wv*16, 64+wv*16}; 4 h col-tiles + 1 e-tile.
// Comb blocks (devp=false) skip the h col-tiles entirely — only e_c is used.
__global__ __launch_bounds__(256, 2) void k_feat(
    const float* __restrict__ device_cont, const int* __restrict__ device_cat,
    const float* __restrict__ de0, const float* __restrict__ de1,
    const float* __restrict__ bd,
    const float* __restrict__ combin_cont, const int* __restrict__ combin_cat,
    const int* __restrict__ combin_idx,
    const float* __restrict__ ce0, const float* __restrict__ ce1,
    const float* __restrict__ bc,
    const float* __restrict__ aW, const uintT* __restrict__ wpack,
    ushortT* __restrict__ h_bf, float* __restrict__ e_d, float* __restrict__ e_c) {
  __shared__ uintT x_s[128 * KP];  // 24,576 B  [row][kpair]
  __shared__ uintT w_s[80 * KP];   // 15,360 B  [col n][kpair], rows 68..79 = 0
  __shared__ int   ci_s[128];

  const int tid  = threadIdx.x;
  const int lane = tid & 63;
  const int wv = __builtin_amdgcn_readfirstlane((int)(tid >> 6));
  const int blk = blockIdx.x;
  const bool devp = blk < NDEVG2;
  const int b0 = (devp ? blk : blk - NDEVG2) * 128;

  if (!devp && tid < 128) ci_s[tid] = combin_idx[b0 + tid];

  // ---- stage W: linear uint4 copy of prepacked slab (816 uint4) + zero tail
  {
    const uint4* __restrict__ wp =
        reinterpret_cast<const uint4*>(wpack + (devp ? 0 : WROWS * KP));
    uint4* __restrict__ ws4 = reinterpret_cast<uint4*>(w_s);
#pragma unroll
    for (int t = 0; t < 4; ++t) {
      const int idx = t * 256 + tid;
      if (idx < 960)                     // 80 rows * 12 uint4
        ws4[idx] = (idx < 816) ? wp[idx] : make_uint4(0u, 0u, 0u, 0u);
    }
  }
  __syncthreads();  // ci_s visible

  // ---- stage x: cont pairs (128*31 = 3968) ----
  {
    const float* __restrict__ cont = devp ? device_cont : combin_cont;
#pragma unroll 1
    for (int e = tid; e < 128 * 31; e += 256) {
      const int r = e / 31, p = e - r * 31;
      const size_t srow = devp ? (size_t)min(b0 + r, NDEV - 1) : (size_t)ci_s[r];
      const float2 v = *reinterpret_cast<const float2*>(cont + srow * CONTF + 2 * p);
      x_s[r * KP + p] = pack2(v.x, v.y);
    }
  }
  // ---- stage embeddings: all 256 threads, one (row, table) each ----
  {
    const int r = tid >> 1, tb = tid & 1;  // r in 0..127
    const int srow = devp ? min(b0 + r, NDEV - 1) : ci_s[r];
    const int cidx = (devp ? device_cat : combin_cat)[2 * srow + tb];
    const float* __restrict__ ep =
        (tb ? (devp ? de1 : ce1) : (devp ? de0 : ce0)) + (size_t)cidx * EMB;
    uintT* __restrict__ dst = &x_s[r * KP + 31 + tb * 8];
#pragma unroll
    for (int k4 = 0; k4 < 4; ++k4) {
      const float4 v = reinterpret_cast<const float4*>(ep)[k4];
      dst[2 * k4 + 0] = pack2(v.x, v.y);
      dst[2 * k4 + 1] = pack2(v.z, v.w);
    }
  }
  if (tid < 128) x_s[tid * KP + 47] = 0u;         // k = 94,95 zero pad
  __syncthreads();

  // ---- MFMA compute ----
  const int m = lane & 15, q = lane >> 4;
  const int aoff = devp ? OUTD : 0;
  const float* bias = uniform_ptr(devp ? bd : bc);
  const float* aWl  = uniform_ptr(aW);

  float4v acc[2][NH];
  if (devp) {
#pragma unroll
    for (int ct = 0; ct < NH; ++ct) {
      const float bv = bias[ct * OUTD + m];
      acc[0][ct] = (float4v){bv, bv, bv, bv};
      acc[1][ct] = (float4v){bv, bv, bv, bv};
    }
  }
  // e-accumulator init: bias-dot const for col hd=m (m<4), else 0
  float bec = 0.f;
  if (m < NH) {
    const float* __restrict__ av = aWl + m * 2 * OUTD + aoff;
#pragma unroll
    for (int o = 0; o < OUTD; ++o) bec = fmaf(bias[m * OUTD + o], av[o], bec);
  }
  float4v acc_e[2];
  acc_e[0] = (float4v){bec, bec, bec, bec};
  acc_e[1] = (float4v){bec, bec, bec, bec};

  const uintT* xa0 = &x_s[(wv * 16 + m) * KP + q * 4];
  const uintT* xa1 = &x_s[(64 + wv * 16 + m) * KP + q * 4];
#pragma unroll
  for (int c = 0; c < 3; ++c) {                  // K chunks of 32
    FragU af0, af1;
    af0.u = *reinterpret_cast<const uint4*>(xa0 + c * 16);
    af1.u = *reinterpret_cast<const uint4*>(xa1 + c * 16);
    if (devp) {
#pragma unroll
      for (int ct = 0; ct < NH; ++ct) {
        FragU bf;
        bf.u = *reinterpret_cast<const uint4*>(&w_s[(ct * 16 + m) * KP + c * 16 + q * 4]);
        acc[0][ct] = __builtin_amdgcn_mfma_f32_16x16x32_bf16(af0.s, bf.s, acc[0][ct], 0, 0, 0);
        acc[1][ct] = __builtin_amdgcn_mfma_f32_16x16x32_bf16(af1.s, bf.s, acc[1][ct], 0, 0, 0);
      }
    }
    FragU bfe;
    bfe.u = *reinterpret_cast<const uint4*>(&w_s[(64 + m) * KP + c * 16 + q * 4]);
    acc_e[0] = __builtin_amdgcn_mfma_f32_16x16x32_bf16(af0.s, bfe.s, acc_e[0], 0, 0, 0);
    acc_e[1] = __builtin_amdgcn_mfma_f32_16x16x32_bf16(af1.s, bfe.s, acc_e[1], 0, 0, 0);
  }

  // ---- epilogue: pure stores (e from acc_e, h from acc) ----
  float* __restrict__ eout = devp ? e_d : e_c;
#pragma unroll
  for (int rt = 0; rt < 2; ++rt) {
    const int rowq = b0 + rt * 64 + wv * 16 + q * 4;  // first of 4 rows
    if (m < NH) {
#pragma unroll
      for (int r = 0; r < 4; ++r)
        if (!devp || rowq + r < NDEV) eout[(size_t)(rowq + r) * NH + m] = acc_e[rt][r];
    }
    if (devp) {
#pragma unroll
      for (int ct = 0; ct < NH; ++ct) {
#pragma unroll
        for (int r = 0; r < 4; ++r) {
          if (rowq + r < NDEV)
            h_bf[(size_t)(rowq + r) * HOUT + ct * OUTD + m] = f2bf(acc[rt][ct][r]);
        }
      }
    }
  }
}

// ---------------- K2: attention + fusion + MLP, fused ----------------------
// v7b: 2 rows per WAVE with per-row small LDS only (19 KB/block — unlike v2's
// 72 KB: residency stays 4 blocks/CU, 16 waves/CU). 16 h-loads in flight per
// lane (vs 8) -> 2x gather concurrency on the latency-bound h_bf stream; all
// weight loads feed two rows. Grid 1024. (v7 compile fix: row1 != param b1.)
__global__ __launch_bounds__(256, 4) void k_attn(
    const int* __restrict__ neighbor_idx, const int* __restrict__ device_idx,
    const int* __restrict__ device_cat, const float* __restrict__ device_cont,
    const float* __restrict__ de0, const float* __restrict__ de1,
    const int* __restrict__ combin_idx, const int* __restrict__ combin_cat,
    const float* __restrict__ combin_cont,
    const float* __restrict__ ce0, const float* __restrict__ ce1,
    const ushortT* __restrict__ h_bf, const float* __restrict__ e_d,
    const float* __restrict__ e_c, const float* __restrict__ ab,
    const float* __restrict__ W1, const float* __restrict__ b1,
    const float* __restrict__ W2, const float* __restrict__ b2,
    const float* __restrict__ W3, const float* __restrict__ b3,
    const float* __restrict__ W4, const float* __restrict__ b4,
    float* __restrict__ out) {
  __shared__ __align__(16) float pb[8][NH][68];
  __shared__ __align__(16) float hb[8][HOUT];
  __shared__ __align__(16) float fusb[8][208];   // fusion row (204 + pad)
  __shared__ __align__(16) float x1b[8][64];

  const int lane = threadIdx.x & 63;
  const int wid  = __builtin_amdgcn_readfirstlane((int)(threadIdx.x >> 6));
  const int row0 = blockIdx.x * 8 + wid * 2;     // this wave's two rows
  const int row1 = row0 + 1;
  const int rl0  = wid * 2, rl1 = rl0 + 1;

  // ---- phase A0: neighbor indices + e gathers issued first, both rows ----
  const int nk0 = neighbor_idx[(size_t)row0 * KNBR + lane];
  const int nk1 = neighbor_idx[(size_t)row1 * KNBR + lane];
  const float4 ed40 = *reinterpret_cast<const float4*>(e_d + (size_t)nk0 * NH);
  const float4 ed41 = *reinterpret_cast<const float4*>(e_d + (size_t)nk1 * NH);
  const float4 ec40 = *reinterpret_cast<const float4*>(e_c + (size_t)row0 * NH);
  const float4 ec41 = *reinterpret_cast<const float4*>(e_c + (size_t)row1 * NH);
  const float4 ab4  = *reinterpret_cast<const float4*>(ab);

  // ---- phase A1: EARLY h_bf prefetch, 16 loads in flight per lane ----
  const int q = lane >> 3, c8 = lane & 7;
  ushort8v hpre0[8], hpre1[8];
#pragma unroll
  for (int t = 0; t < 8; ++t) {
    const int nt0 = __shfl(nk0, q * 8 + t);
    const int nt1 = __shfl(nk1, q * 8 + t);
    hpre0[t] = *reinterpret_cast<const ushort8v*>(h_bf + (size_t)nt0 * HOUT + c8 * 8);
    hpre1[t] = *reinterpret_cast<const ushort8v*>(h_bf + (size_t)nt1 * HOUT + c8 * 8);
  }

  // ---- phase A2: gather fusion features [comb 94 | dev 94], both rows ----
#pragma unroll
  for (int r2 = 0; r2 < 2; ++r2) {
    const int bb_ = r2 ? row1 : row0;
    const int rl  = r2 ? rl1 : rl0;
    const int ci = combin_idx[bb_];
    const int cc0 = combin_cat[2 * ci], cc1 = combin_cat[2 * ci + 1];
    const int didx = device_idx[bb_];
    const int dc0 = device_cat[2 * didx], dc1 = device_cat[2 * didx + 1];
#pragma unroll
    for (int t = 0; t < 3; ++t) {
      const int i = lane + t * 64;
      if (i < 188) {
        float v;
        if (i < 62)       v = combin_cont[(size_t)ci * CONTF + i];
        else if (i < 78)  v = ce0[(size_t)cc0 * EMB + (i - 62)];
        else if (i < 94)  v = ce1[(size_t)cc1 * EMB + (i - 78)];
        else if (i < 156) v = device_cont[(size_t)didx * CONTF + (i - 94)];
        else if (i < 172) v = de0[(size_t)dc0 * EMB + (i - 156)];
        else              v = de1[(size_t)dc1 * EMB + (i - 172)];
        fusb[rl][i] = v;
      }
    }
  }

  // ---- phase A3: softmax (lane = k), no max-subtract, both rows ----
  {
    float u0 = ec40.x + ed40.x + ab4.x;
    float u1 = ec40.y + ed40.y + ab4.y;
    float u2 = ec40.z + ed40.z + ab4.z;
    float u3 = ec40.w + ed40.w + ab4.w;
    float w0 = ec41.x + ed41.x + ab4.x;
    float w1 = ec41.y + ed41.y + ab4.y;
    float w2 = ec41.z + ed41.z + ab4.z;
    float w3 = ec41.w + ed41.w + ab4.w;
    u0 = u0 > 0.f ? u0 : ALPHA * u0;  u1 = u1 > 0.f ? u1 : ALPHA * u1;
    u2 = u2 > 0.f ? u2 : ALPHA * u2;  u3 = u3 > 0.f ? u3 : ALPHA * u3;
    w0 = w0 > 0.f ? w0 : ALPHA * w0;  w1 = w1 > 0.f ? w1 : ALPHA * w1;
    w2 = w2 > 0.f ? w2 : ALPHA * w2;  w3 = w3 > 0.f ? w3 : ALPHA * w3;

    float p00 = expf(u0), p01 = expf(u1), p02 = expf(u2), p03 = expf(u3);
    float p10 = expf(w0), p11 = expf(w1), p12 = expf(w2), p13 = expf(w3);
    float s00 = p00, s01 = p01, s02 = p02, s03 = p03;
    float s10 = p10, s11 = p11, s12 = p12, s13 = p13;
#pragma unroll
    for (int msk = 1; msk < 64; msk <<= 1) {
      s00 += __shfl_xor(s00, msk);  s01 += __shfl_xor(s01, msk);
      s02 += __shfl_xor(s02, msk);  s03 += __shfl_xor(s03, msk);
      s10 += __shfl_xor(s10, msk);  s11 += __shfl_xor(s11, msk);
      s12 += __shfl_xor(s12, msk);  s13 += __shfl_xor(s13, msk);
    }
    pb[rl0][0][lane] = p00 / s00;
    pb[rl0][1][lane] = p01 / s01;
    pb[rl0][2][lane] = p02 / s02;
    pb[rl0][3][lane] = p03 / s03;
    pb[rl1][0][lane] = p10 / s10;
    pb[rl1][1][lane] = p11 / s11;
    pb[rl1][2][lane] = p12 / s12;
    pb[rl1][3][lane] = p13 / s13;
  }
  __builtin_amdgcn_wave_barrier();

  // ---- phase B: weighted sums from prefetched h regs, lane = (q, c8) ----
  {
    const int hq = c8 >> 1;
#pragma unroll
    for (int r2 = 0; r2 < 2; ++r2) {
      const int rl = r2 ? rl1 : rl0;
      const float4 pA4 = *reinterpret_cast<const float4*>(&pb[rl][hq][q * 8]);
      const float4 pB4 = *reinterpret_cast<const float4*>(&pb[rl][hq][q * 8 + 4]);
      const float pv[8] = {pA4.x, pA4.y, pA4.z, pA4.w,
                           pB4.x, pB4.y, pB4.z, pB4.w};
      float a[8];
#pragma unroll
      for (int i = 0; i < 8; ++i) a[i] = 0.f;
#pragma unroll
      for (int t = 0; t < 8; ++t) {
        const float p = pv[t];
        const ushort8v hv = r2 ? hpre1[t] : hpre0[t];
#pragma unroll
        for (int i = 0; i < 8; ++i) a[i] = fmaf(p, bf2f(hv[i]), a[i]);
      }
#pragma unroll
      for (int msk = 8; msk < 64; msk <<= 1) {
#pragma unroll
        for (int i = 0; i < 8; ++i) a[i] += __shfl_xor(a[i], msk);
      }
      if (q == 0) {
#pragma unroll
        for (int i = 0; i < 8; ++i) a[i] = a[i] > 0.f ? a[i] : expm1f(a[i]);
        float4* hp = reinterpret_cast<float4*>(&hb[rl][c8 * 8]);
        hp[0] = make_float4(a[0], a[1], a[2], a[3]);
        hp[1] = make_float4(a[4], a[5], a[6], a[7]);
      }
    }
  }
  __builtin_amdgcn_wave_barrier();

  // ---- phase C: attn_feats = head_out(64) @ W1(64x16) + b1, both rows ----
  {
    const int j = lane & 15, gg = lane >> 4;
    const float4* hv40 = reinterpret_cast<const float4*>(&hb[rl0][gg * 16]);
    const float4* hv41 = reinterpret_cast<const float4*>(&hb[rl1][gg * 16]);
    float pa0 = 0.f, pa1 = 0.f, pb0_ = 0.f, pb1_ = 0.f;
#pragma unroll
    for (int t4 = 0; t4 < 4; ++t4) {
      const float4 h0 = hv40[t4];
      const float4 h1 = hv41[t4];
      const int tb = gg * 16 + t4 * 4;
      const float wA = W1[(tb + 0) * OUTD + j];
      const float wB = W1[(tb + 1) * OUTD + j];
      const float wC = W1[(tb + 2) * OUTD + j];
      const float wD = W1[(tb + 3) * OUTD + j];
      pa0 = fmaf(h0.x, wA, pa0);  pb0_ = fmaf(h1.x, wA, pb0_);
      pa1 = fmaf(h0.y, wB, pa1);  pb1_ = fmaf(h1.y, wB, pb1_);
      pa0 = fmaf(h0.z, wC, pa0);  pb0_ = fmaf(h1.z, wC, pb0_);
      pa1 = fmaf(h0.w, wD, pa1);  pb1_ = fmaf(h1.w, wD, pb1_);
    }
    float part0 = pa0 + pa1;
    float part1 = pb0_ + pb1_;
    part0 += __shfl_xor(part0, 16);
    part0 += __shfl_xor(part0, 32);
    part1 += __shfl_xor(part1, 16);
    part1 += __shfl_xor(part1, 32);
    if (lane < 16) {
      const float bb = b1[lane];
      fusb[rl0][188 + lane] = part0 + bb;
      fusb[rl1][188 + lane] = part1 + bb;
    }
  }
  __builtin_amdgcn_wave_barrier();

  // ---- phase D: MLP layer 1 (204 -> 64), lane = output col; b128 reads ----
  {
    float a00 = b2[lane], a01 = 0.f, a02 = 0.f, a03 = 0.f;
    float a10 = a00,      a11 = 0.f, a12 = 0.f, a13 = 0.f;
    const float4* fu40 = reinterpret_cast<const float4*>(fusb[rl0]);
    const float4* fu41 = reinterpret_cast<const float4*>(fusb[rl1]);
#pragma unroll 3
    for (int f4 = 0; f4 < 51; ++f4) {
      const float4 u0 = fu40[f4];
      const float4 u1 = fu41[f4];
      const int fb = f4 * 4;
      const float wA = W2[(fb + 0) * 64 + lane];
      const float wB = W2[(fb + 1) * 64 + lane];
      const float wC = W2[(fb + 2) * 64 + lane];
      const float wD = W2[(fb + 3) * 64 + lane];
      a00 = fmaf(u0.x, wA, a00);  a10 = fmaf(u1.x, wA, a10);
      a01 = fmaf(u0.y, wB, a01);  a11 = fmaf(u1.y, wB, a11);
      a02 = fmaf(u0.z, wC, a02);  a12 = fmaf(u1.z, wC, a12);
      a03 = fmaf(u0.w, wD, a03);  a13 = fmaf(u1.w, wD, a13);
    }
    x1b[rl0][lane] = fmaxf((a00 + a01) + (a02 + a03), 0.f);
    x1b[rl1][lane] = fmaxf((a10 + a11) + (a12 + a13), 0.f);
  }
  __builtin_amdgcn_wave_barrier();

  // ---- layers 2+3 + sigmoid, both rows ----
  const int m = lane & 31, rh = lane >> 5;
  {
    float xa0 = rh ? 0.f : b3[m], xa1 = 0.f, xa2 = 0.f, xa3 = 0.f;
    float xb0 = rh ? 0.f : b3[m], xb1 = 0.f, xb2 = 0.f, xb3 = 0.f;
    const float4* xv40 = reinterpret_cast<const float4*>(&x1b[rl0][rh * 32]);
    const float4* xv41 = reinterpret_cast<const float4*>(&x1b[rl1][rh * 32]);
#pragma unroll
    for (int j4 = 0; j4 < 8; ++j4) {
      const float4 x0 = xv40[j4];
      const float4 x1 = xv41[j4];
      const int jb = rh * 32 + j4 * 4;
      const float wA = W3[(jb + 0) * 32 + m];
      const float wB = W3[(jb + 1) * 32 + m];
      const float wC = W3[(jb + 2) * 32 + m];
      const float wD = W3[(jb + 3) * 32 + m];
      xa0 = fmaf(x0.x, wA, xa0);  xb0 = fmaf(x1.x, wA, xb0);
      xa1 = fmaf(x0.y, wB, xa1);  xb1 = fmaf(x1.y, wB, xb1);
      xa2 = fmaf(x0.z, wC, xa2);  xb2 = fmaf(x1.z, wC, xb2);
      xa3 = fmaf(x0.w, wD, xa3);  xb3 = fmaf(x1.w, wD, xb3);
    }
    float x20 = (xa0 + xa1) + (xa2 + xa3);
    float x21 = (xb0 + xb1) + (xb2 + xb3);
    x20 += __shfl_xor(x20, 32);
    x21 += __shfl_xor(x21, 32);
    const float w4 = W4[m];
    float pL0 = fmaxf(x20, 0.f) * w4;
    float pL1 = fmaxf(x21, 0.f) * w4;
#pragma unroll
    for (int msk = 1; msk < 32; msk <<= 1) {
      pL0 += __shfl_xor(pL0, msk);
      pL1 += __shfl_xor(pL1, msk);
    }
    if (lane == 0) {
      const float bz = b4[0];
      out[row0] = 1.f / (1.f + expf(-(pL0 + bz)));
      out[row1] = 1.f / (1.f + expf(-(pL1 + bz)));
    }
  }
}

extern "C" void kernel_launch(void* const* d_in, const int* in_sizes, int n_in,
                              void* d_out, int out_size, void* d_ws, size_t ws_size,
                              hipStream_t stream) {
  const float* combin_cont  = (const float*)d_in[0];
  const int*   combin_cat   = (const int*)d_in[1];
  const float* device_cont  = (const float*)d_in[2];
  const int*   device_cat   = (const int*)d_in[3];
  const int*   combin_idx   = (const int*)d_in[4];
  const int*   device_idx   = (const int*)d_in[5];
  const int*   neighbor_idx = (const int*)d_in[6];
  const float* ce0 = (const float*)d_in[7];
  const float* ce1 = (const float*)d_in[8];
  const float* de0 = (const float*)d_in[9];
  const float* de1 = (const float*)d_in[10];
  const float* Wc  = (const float*)d_in[11];
  const float* bc  = (const float*)d_in[12];
  const float* Wd  = (const float*)d_in[13];
  const float* bd  = (const float*)d_in[14];
  const float* aW  = (const float*)d_in[15];
  const float* ab  = (const float*)d_in[16];
  const float* W1  = (const float*)d_in[17];
  const float* b1  = (const float*)d_in[18];
  const float* W2  = (const float*)d_in[19];
  const float* b2  = (const float*)d_in[20];
  const float* W3  = (const float*)d_in[21];
  const float* b3  = (const float*)d_in[22];
  const float* W4  = (const float*)d_in[23];
  const float* b4  = (const float*)d_in[24];

  float* ws  = (float*)d_ws;
  ushortT* h_bf = (ushortT*)ws;
  float* e_d = ws + 3200000;
  float* e_c = ws + 3600000;
  uintT* wpack = (uintT*)(ws + 3632768);

  k_prep<<<26, 256, 0, stream>>>(Wd, Wc, aW, wpack);
  k_feat<<<NDEVG2 + NCOMBG2, 256, 0, stream>>>(
      device_cont, device_cat, de0, de1, bd,
      combin_cont, combin_cat, combin_idx, ce0, ce1, bc, aW, wpack,
      h_bf, e_d, e_c);
  k_attn<<<NBATCH / 8, 256, 0, stream>>>(
      neighbor_idx, device_idx, device_cat, device_cont, de0, de1,
      combin_idx, combin_cat, combin_cont, ce0, ce1,
      h_bf, e_d, e_c, ab, W1, b1, W2, b2, W3, b3, W4, b4, (float*)d_out);
}